// Round 1
// baseline (255.723 us; speedup 1.0000x reference)
//
#include <hip/hip_runtime.h>

#define BATCH 2
#define NVIEW 4
#define NJOINT 24
#define HM 96
#define VOLD 48
#define NVOX (VOLD*VOLD*VOLD)   // 110592

constexpr int TPB = 256;
constexpr int VPT = 8;            // voxels per thread
constexpr int BN  = TPB * VPT;    // 2048 voxels per block
constexpr int NCHUNK = NVOX / BN; // 54 (exact)

// acc layout: [B*J][4] = {sum_w, sum_wx, sum_wy, sum_wz}
__global__ __launch_bounds__(TPB) void vol_acc_kernel(
    const float* __restrict__ hm,   // (B,V,J,HM,HM)
    const float* __restrict__ pm,   // (B,V,3,4)
    const float* __restrict__ cv,   // (B,48,48,48,3)
    float* __restrict__ acc)
{
    const int bj = blockIdx.y;
    const int b  = bj / NJOINT;
    const int j  = bj - b * NJOINT;

    // Projection rows for the 4 views (uniform across block -> scalar loads)
    float M[NVIEW][12];
#pragma unroll
    for (int v = 0; v < NVIEW; ++v) {
#pragma unroll
        for (int k = 0; k < 12; ++k) M[v][k] = pm[(b * NVIEW + v) * 12 + k];
    }

    const float* img0 = hm + ((size_t)(b * NVIEW) * NJOINT + j) * (HM * HM);
    const float* cvb  = cv + (size_t)b * NVOX * 3;
    const int n0 = blockIdx.x * BN + threadIdx.x;

    float sw = 0.f, sx = 0.f, sy = 0.f, sz = 0.f;

#pragma unroll
    for (int k = 0; k < VPT; ++k) {
        const int n = n0 + k * TPB;
        const float X = cvb[n * 3 + 0];
        const float Y = cvb[n * 3 + 1];
        const float Z = cvb[n * 3 + 2];
        float vol = 0.f;
#pragma unroll
        for (int v = 0; v < NVIEW; ++v) {
            const float* m  = M[v];
            const float pz  = m[8]*X + m[9]*Y + m[10]*Z + m[11];
            const float pxn = m[0]*X + m[1]*Y + m[2]*Z + m[3];
            const float pyn = m[4]*X + m[5]*Y + m[6]*Z + m[7];
            if (pz > 0.f) {
                const float inv = 1.0f / pz;
                // ix = px/HM*(HM-1), same for iy (square heatmap)
                const float ix = pxn * inv * (95.0f / 96.0f);
                const float iy = pyn * inv * (95.0f / 96.0f);
                const float x0f = floorf(ix), y0f = floorf(iy);
                const float wx1 = ix - x0f, wy1 = iy - y0f;
                const float wx0 = 1.f - wx1, wy0 = 1.f - wy1;
                const int x0 = (int)x0f, y0 = (int)y0f;
                const int x1 = x0 + 1,  y1 = y0 + 1;
                const bool vx0 = (unsigned)x0 < (unsigned)HM;
                const bool vx1 = (unsigned)x1 < (unsigned)HM;
                const bool vy0 = (unsigned)y0 < (unsigned)HM;
                const bool vy1 = (unsigned)y1 < (unsigned)HM;
                const int xc0 = min(max(x0, 0), HM - 1);
                const int xc1 = min(max(x1, 0), HM - 1);
                const int yc0 = min(max(y0, 0), HM - 1);
                const int yc1 = min(max(y1, 0), HM - 1);
                const float* img = img0 + (size_t)v * (NJOINT * HM * HM);
                const float v00 = img[yc0 * HM + xc0];
                const float v01 = img[yc0 * HM + xc1];
                const float v10 = img[yc1 * HM + xc0];
                const float v11 = img[yc1 * HM + xc1];
                float s = 0.f;
                s += wy0 * wx0 * ((vy0 && vx0) ? v00 : 0.f);
                s += wy0 * wx1 * ((vy0 && vx1) ? v01 : 0.f);
                s += wy1 * wx0 * ((vy1 && vx0) ? v10 : 0.f);
                s += wy1 * wx1 * ((vy1 && vx1) ? v11 : 0.f);
                vol += s;
            }
        }
        // softmax without max-subtraction: vol in [0,4], exp(4)~54.6, safe in fp32
        const float w = __expf(vol);
        sw += w;
        sx += w * X;
        sy += w * Y;
        sz += w * Z;
    }

    // wave64 butterfly reduce, then one atomic per wave per accumulator
#pragma unroll
    for (int off = 32; off > 0; off >>= 1) {
        sw += __shfl_down(sw, off);
        sx += __shfl_down(sx, off);
        sy += __shfl_down(sy, off);
        sz += __shfl_down(sz, off);
    }
    if ((threadIdx.x & 63) == 0) {
        atomicAdd(&acc[bj * 4 + 0], sw);
        atomicAdd(&acc[bj * 4 + 1], sx);
        atomicAdd(&acc[bj * 4 + 2], sy);
        atomicAdd(&acc[bj * 4 + 3], sz);
    }
}

__global__ void finalize_kernel(const float* __restrict__ acc, float* __restrict__ out)
{
    const int i = threadIdx.x;
    if (i < BATCH * NJOINT * 3) {
        const int bj = i / 3;
        const int c  = i - bj * 3;
        out[i] = acc[bj * 4 + 1 + c] / acc[bj * 4 + 0];
    }
}

extern "C" void kernel_launch(void* const* d_in, const int* in_sizes, int n_in,
                              void* d_out, int out_size, void* d_ws, size_t ws_size,
                              hipStream_t stream)
{
    const float* hm = (const float*)d_in[0];   // heatmaps (B,V,J,96,96)
    const float* pm = (const float*)d_in[1];   // proj_matricies (B,V,3,4)
    const float* cv = (const float*)d_in[2];   // coord_volumes (B,48,48,48,3)
    float* out = (float*)d_out;                // (B,J,3)
    float* acc = (float*)d_ws;                 // B*J*4 floats

    hipMemsetAsync(acc, 0, BATCH * NJOINT * 4 * sizeof(float), stream);

    dim3 grid(NCHUNK, BATCH * NJOINT);
    vol_acc_kernel<<<grid, TPB, 0, stream>>>(hm, pm, cv, acc);
    finalize_kernel<<<1, 192, 0, stream>>>(acc, out);
}